// Round 1
// 294.612 us; speedup vs baseline: 1.0193x; 1.0193x over previous
//
#include <hip/hip_runtime.h>
#include <hip/hip_bf16.h>

// Problem: B=4096, N=64, H=256 (all fixed). All inputs fp32, output fp32.
#define BATCH 4096
#define NMEM  64
#define HDIM  256
#define MROWS 320   // 256 W_w rows + 64 (h+w) rows

typedef __attribute__((ext_vector_type(8))) short short8;   // 8 bf16 = 4 VGPRs (MFMA A/B frag)
typedef __attribute__((ext_vector_type(4))) float floatx4;  // MFMA C/D frag

__device__ __forceinline__ float bf2f(unsigned short u) {
    union { unsigned int i; float f; } v; v.i = ((unsigned int)u) << 16; return v.f;
}
__device__ __forceinline__ unsigned short f2bf(float f) {
    union { float f; unsigned int i; } v; v.f = f;
    unsigned int x = v.i;
    return (unsigned short)((x + 0x7FFFu + ((x >> 16) & 1u)) >> 16);  // RNE
}
__device__ __forceinline__ short8 pack_bf16x8(float4 f0, float4 f1) {
    short8 a;
    a[0] = (short)f2bf(f0.x); a[1] = (short)f2bf(f0.y);
    a[2] = (short)f2bf(f0.z); a[3] = (short)f2bf(f0.w);
    a[4] = (short)f2bf(f1.x); a[5] = (short)f2bf(f1.y);
    a[6] = (short)f2bf(f1.z); a[7] = (short)f2bf(f1.w);
    return a;
}

// ---------------------------------------------------------------------------
// Kernel 1: prep (unchanged from validated version).
//  blocks 0..15 : A = [h|w] @ [U|V]^T via MFMA (K=512). Block j -> cols
//                 j*16..+15; wave w -> rows w*16..+15.
//  blocks 16..31: M rows, 20 rows/block, coalesced:
//                 M[r] = bf16(W_w[r]) for r<256, else bf16(h[r-256]+w[r-256]).
// ---------------------------------------------------------------------------
__global__ __launch_bounds__(256) void prep_kernel(
    const float* __restrict__ h,
    const float* __restrict__ w,
    const float* __restrict__ U_w,
    const float* __restrict__ V_w,
    const float* __restrict__ W_w,
    unsigned short* __restrict__ M,    // [320][256] bf16
    unsigned short* __restrict__ A)    // [64][256]  bf16
{
    const int bid = blockIdx.x;
    const int t   = threadIdx.x;
    if (bid < 16) {
        const int wv   = t >> 6;
        const int lane = t & 63;
        const int m = lane & 15;
        const int q = lane >> 4;
        const int j0 = bid * 16;

        const float* ah = h   + (size_t)(wv * 16 + m) * HDIM;
        const float* aw = w   + (size_t)(wv * 16 + m) * HDIM;
        const float* bu = U_w + (size_t)(j0 + m) * HDIM;
        const float* bv = V_w + (size_t)(j0 + m) * HDIM;

        floatx4 acc = {0.f, 0.f, 0.f, 0.f};
        #pragma unroll
        for (int ks = 0; ks < 16; ++ks) {
            const float* asrc = (ks < 8) ? ah : aw;
            const float* bsrc = (ks < 8) ? bu : bv;
            const int off = (ks & 7) * 32 + q * 8;
            float4 a0 = *(const float4*)(asrc + off);
            float4 a1 = *(const float4*)(asrc + off + 4);
            float4 b0 = *(const float4*)(bsrc + off);
            float4 b1 = *(const float4*)(bsrc + off + 4);
            acc = __builtin_amdgcn_mfma_f32_16x16x32_bf16(
                pack_bf16x8(a0, a1), pack_bf16x8(b0, b1), acc, 0, 0, 0);
        }
        #pragma unroll
        for (int r = 0; r < 4; ++r)
            A[(size_t)(wv * 16 + q * 4 + r) * HDIM + j0 + m] = f2bf(acc[r]);
    } else {
        const int r0 = (bid - 16) * 20;
        for (int rr = 0; rr < 20; ++rr) {
            const int r = r0 + rr;
            float v;
            if (r < 256) v = W_w[(size_t)r * HDIM + t];
            else         v = h[(size_t)(r - 256) * HDIM + t] + w[(size_t)(r - 256) * HDIM + t];
            M[(size_t)r * HDIM + t] = f2bf(v);
        }
    }
}

// ---------------------------------------------------------------------------
// Kernel 2: fused GEMM + elementwise + normalize.
// Grid = 1024 blocks = (4096/16 batch tiles) x (4 N-quadrants), 256 thr.
//   b0 = (bid>>2)*16 batches, n0 = (bid&3)*16 rows of N.
// Phase 1 (MFMA, validated fragment layout from previous rounds):
//   C_lds[16][256] = s_t[b0..+16] @ W_w^T   (16 j-tiles, 4 per wave)
//   g_lds[16][16]  = sigmoid(s_t @ (h+w)[n0..+16]^T)  (1 tile, wave 3)
//   A frag: lane l elem j -> A[m=l&15][k=(l>>4)*8+j]
//   D     : lane l reg  r -> D[row=(l>>4)*4+r][col=l&15]
// The 4x redundant MFMA work across N-quadrants is ~1 us total (matrix pipe
// is 0.03% utilized) and buys 4 blocks/CU of occupancy for the store phase.
// Phase 2 (quarter-wave per row, as in validated fuse_kernel):
//   lane: quarter q owns row n = n0 + wave*4 + q; lanes m cover cols m*4+j*64.
//   h/A rows are batch-invariant -> loaded ONCE into registers, reused for
//   all 16 batches. C broadcast from LDS. 4-step shfl_xor row reduction.
// LDS = 17 KB/block -> 4 blocks/CU fits (68 KB); launch_bounds caps VGPR<=128.
// ---------------------------------------------------------------------------
__global__ __launch_bounds__(256, 4) void fused_kernel(
    const float* __restrict__ s_t,           // [4096][256] f32
    const float* __restrict__ h,             // [64][256]   f32
    const unsigned short* __restrict__ M,    // [320][256]  bf16
    const unsigned short* __restrict__ A,    // [64][256]   bf16
    const float* __restrict__ prelu_a,       // [1] f32
    float* __restrict__ out)                 // [4096][64][256] f32
{
    __shared__ float C_lds[16][HDIM];   // 16 KB: C[b_local][k]
    __shared__ float g_lds[16][16];     // 1 KB:  g[b_local][n_local]

    const int b0 = (blockIdx.x >> 2) * 16;
    const int n0 = (blockIdx.x & 3) * 16;
    const int t    = threadIdx.x;
    const int wave = t >> 6;
    const int lane = t & 63;
    const int m = lane & 15;
    const int q = lane >> 4;

    // ---- Phase 1: C tile + gate tile via MFMA ----
    const float* arow = s_t + (size_t)(b0 + m) * HDIM;
    short8 afrag[8];
    #pragma unroll
    for (int ks = 0; ks < 8; ++ks) {
        const int base = ks * 32 + q * 8;
        afrag[ks] = pack_bf16x8(*(const float4*)(arow + base),
                                *(const float4*)(arow + base + 4));
    }
    #pragma unroll
    for (int i = 0; i < 4; ++i) {
        const int j0 = (wave * 4 + i) * 16;
        const short8* brow = (const short8*)(M + (size_t)(j0 + m) * HDIM);
        floatx4 acc = {0.f, 0.f, 0.f, 0.f};
        #pragma unroll
        for (int ks = 0; ks < 8; ++ks)
            acc = __builtin_amdgcn_mfma_f32_16x16x32_bf16(
                afrag[ks], brow[ks * 4 + q], acc, 0, 0, 0);
        #pragma unroll
        for (int r = 0; r < 4; ++r)
            C_lds[q * 4 + r][j0 + m] = acc[r];
    }
    if (wave == 3) {
        // gate logits for this block's 16 N-rows: M rows 256+n0 .. +15
        const short8* brow = (const short8*)(M + (size_t)(256 + n0 + m) * HDIM);
        floatx4 acc = {0.f, 0.f, 0.f, 0.f};
        #pragma unroll
        for (int ks = 0; ks < 8; ++ks)
            acc = __builtin_amdgcn_mfma_f32_16x16x32_bf16(
                afrag[ks], brow[ks * 4 + q], acc, 0, 0, 0);
        #pragma unroll
        for (int r = 0; r < 4; ++r)
            g_lds[q * 4 + r][m] = 1.f / (1.f + __expf(-acc[r]));
    }
    __syncthreads();

    // ---- Phase 2: elementwise + row L2-normalize, 16 batches ----
    const float pa = prelu_a[0];
    const int nl = wave * 4 + q;        // local N row 0..15
    const int n  = n0 + nl;             // global N row
    const float* hrow = h + (size_t)n * HDIM;
    const unsigned short* Arow = A + (size_t)n * HDIM;

    // batch-invariant row data: load once, keep in registers
    float hv[16], av[16];
    #pragma unroll
    for (int j = 0; j < 4; ++j) {
        const int k = m * 4 + j * 64;
        float4  h4 = *(const float4*)(hrow + k);
        ushort4 a4 = *(const ushort4*)(Arow + k);
        hv[j * 4 + 0] = h4.x; hv[j * 4 + 1] = h4.y;
        hv[j * 4 + 2] = h4.z; hv[j * 4 + 3] = h4.w;
        av[j * 4 + 0] = bf2f(a4.x); av[j * 4 + 1] = bf2f(a4.y);
        av[j * 4 + 2] = bf2f(a4.z); av[j * 4 + 3] = bf2f(a4.w);
    }

    #pragma unroll 2
    for (int b = 0; b < 16; ++b) {
        const float g = g_lds[b][nl];
        float y[16];
        float ss = 0.f;
        #pragma unroll
        for (int j = 0; j < 4; ++j) {
            const int k = m * 4 + j * 64;
            float4 cv = *(const float4*)(&C_lds[b][k]);
            float x0 = av[j * 4 + 0] + cv.x;
            float x1 = av[j * 4 + 1] + cv.y;
            float x2 = av[j * 4 + 2] + cv.z;
            float x3 = av[j * 4 + 3] + cv.w;
            x0 = (x0 >= 0.f) ? x0 : pa * x0;
            x1 = (x1 >= 0.f) ? x1 : pa * x1;
            x2 = (x2 >= 0.f) ? x2 : pa * x2;
            x3 = (x3 >= 0.f) ? x3 : pa * x3;
            float y0 = hv[j * 4 + 0] + g * x0;
            float y1 = hv[j * 4 + 1] + g * x1;
            float y2 = hv[j * 4 + 2] + g * x2;
            float y3 = hv[j * 4 + 3] + g * x3;
            y[j * 4 + 0] = y0; y[j * 4 + 1] = y1;
            y[j * 4 + 2] = y2; y[j * 4 + 3] = y3;
            ss += y0 * y0 + y1 * y1 + y2 * y2 + y3 * y3;
        }
        // reduce across the 16-lane quarter (xor offsets stay in-quarter)
        ss += __shfl_xor(ss, 1);
        ss += __shfl_xor(ss, 2);
        ss += __shfl_xor(ss, 4);
        ss += __shfl_xor(ss, 8);
        const float rn = rsqrtf(ss);

        float* orow = out + ((size_t)(b0 + b) * NMEM + n) * HDIM;
        #pragma unroll
        for (int j = 0; j < 4; ++j) {
            float4 ov;
            ov.x = y[j * 4 + 0] * rn;
            ov.y = y[j * 4 + 1] * rn;
            ov.z = y[j * 4 + 2] * rn;
            ov.w = y[j * 4 + 3] * rn;
            *(float4*)(orow + m * 4 + j * 64) = ov;
        }
    }
}

// ---------------------------------------------------------------------------
extern "C" void kernel_launch(void* const* d_in, const int* in_sizes, int n_in,
                              void* d_out, int out_size, void* d_ws, size_t ws_size,
                              hipStream_t stream) {
    const float* s_t     = (const float*)d_in[0];
    const float* h       = (const float*)d_in[1];
    const float* w       = (const float*)d_in[2];
    const float* U_w     = (const float*)d_in[3];
    const float* V_w     = (const float*)d_in[4];
    const float* W_w     = (const float*)d_in[5];
    const float* prelu_a = (const float*)d_in[6];
    float* out = (float*)d_out;

    // ws layout: M bf16 [320][256] (160KB) | A bf16 [64][256] (32KB)
    unsigned short* M = (unsigned short*)d_ws;
    unsigned short* A = (unsigned short*)((char*)d_ws + MROWS * HDIM * 2);

    prep_kernel<<<32, 256, 0, stream>>>(h, w, U_w, V_w, W_w, M, A);
    fused_kernel<<<(BATCH / 16) * 4, 256, 0, stream>>>(s_t, h, M, A, prelu_a, out);
}